// Round 7
// baseline (259.763 us; speedup 1.0000x reference)
//
#include <hip/hip_runtime.h>
#include <stdint.h>

#define D_DIM 4096
#define N_ROWS 8192

typedef __attribute__((ext_vector_type(8))) short bfrag8;
typedef __attribute__((ext_vector_type(4))) float facc4;
typedef unsigned long long u64;

__device__ __forceinline__ uint32_t pack_bf16x2(float lo, float hi) {
    union { float f; uint32_t u; } a, b;
    a.f = lo; b.f = hi;
    return (b.u & 0xFFFF0000u) | (a.u >> 16);   // truncate-to-bf16
}

// ---------------------------------------------------------------------------
// Kernel 0: frag-ordered bf16 B-image from A (verified since round 3).
// Granule fb = chunk*16 + t*2 + ks; slot = fb*64 + lane (16 B):
//   A[16t + (lane&15)][chunk*64 + ks*32 + (lane>>4)*8 + j], j=0..7
// ---------------------------------------------------------------------------
__global__ void __launch_bounds__(256)
prep_A(const float* __restrict__ A, uint32_t* __restrict__ Bimg) {
    const int S = blockIdx.x * 256 + threadIdx.x;  // 0..65535
    const int chunk = S >> 10;
    const int rest  = S & 1023;
    const int tks   = rest >> 6;
    const int lane  = rest & 63;
    const int t  = tks >> 1;
    const int ks = tks & 1;
    const int c  = lane & 15;
    const int q  = lane >> 4;
    const float* src = A + (size_t)(16 * t + c) * D_DIM + chunk * 64 + ks * 32 + q * 8;
    float4 f0 = *(const float4*)(src);
    float4 f1 = *(const float4*)(src + 4);
    uint4 o;
    o.x = pack_bf16x2(f0.x, f0.y);
    o.y = pack_bf16x2(f0.z, f0.w);
    o.z = pack_bf16x2(f1.x, f1.y);
    o.w = pack_bf16x2(f1.z, f1.w);
    *(uint4*)(Bimg + (size_t)S * 4) = o;
}

// ---------------------------------------------------------------------------
// Kernel 1: DISCRIMINATOR. Pure grid-strided stream: L fp32 -> Lb bf16,
// row-major layout unchanged. Contiguous 32-B loads / 16-B stores per lane,
// no transpose, no LDS. Structurally = the 6.3 TB/s m13 copy.
// ---------------------------------------------------------------------------
__global__ void __launch_bounds__(256)
copy_bf16(const float* __restrict__ L, uint32_t* __restrict__ Lb) {
    const size_t total  = (size_t)N_ROWS * D_DIM / 8;       // groups of 8 floats
    const size_t stride = (size_t)gridDim.x * 256;
    for (size_t i = blockIdx.x * 256 + threadIdx.x; i < total; i += stride) {
        const float* p = L + i * 8;
        float4 f0 = *(const float4*)(p);
        float4 f1 = *(const float4*)(p + 4);
        uint4 o;
        o.x = pack_bf16x2(f0.x, f0.y);
        o.y = pack_bf16x2(f0.z, f0.w);
        o.z = pack_bf16x2(f1.x, f1.y);
        o.w = pack_bf16x2(f1.z, f1.w);
        *(uint4*)(Lb + i * 4) = o;
    }
}

// ---------------------------------------------------------------------------
// Kernel 2: R3's verified barrier-free direct-register GEMM, now reading the
// compact bf16 Lb (half the bytes, A-frag = single b128 load, no pack VALU).
// Split-K S=8 -> 4096 waves (16 waves/CU). Writes fp32 partial planes.
// ---------------------------------------------------------------------------
__global__ void __launch_bounds__(256)
gemm_direct_b(const uint32_t* __restrict__ Lb, const uint32_t* __restrict__ Bimg,
              float* __restrict__ partials, int kpb) {
    const int tid  = threadIdx.x;
    const int lane = tid & 63;
    const int gw   = blockIdx.x * 4 + (tid >> 6);
    const int split = gw >> 9;                      // 512 waves per split
    const int mwave = gw & 511;
    const int c = lane & 15;
    const int q = lane >> 4;
    // lane's A-row in u32 units (bf16 row = 2048 u32); q*8 bf16 = q*4 u32
    const uint32_t* lrow = Lb + (size_t)(16 * mwave + c) * (D_DIM / 2) + q * 4;

    facc4 acc[8];
#pragma unroll
    for (int t = 0; t < 8; t++) acc[t] = (facc4){0.f, 0.f, 0.f, 0.f};

    const int k0 = split * kpb;
#pragma unroll 2
    for (int k = k0; k < k0 + kpb; k++) {
        const int kc = k * 32;                      // 64 bf16 = 32 u32
        bfrag8 a0 = *(const bfrag8*)(lrow + kc);        // k-elems q*8..q*8+7
        bfrag8 a1 = *(const bfrag8*)(lrow + kc + 16);   // +32 bf16
        const uint32_t* bbase = Bimg + ((size_t)k * 16) * 256 + lane * 4;
#pragma unroll
        for (int t = 0; t < 8; t++) {
            bfrag8 b0 = *(const bfrag8*)(bbase + (t * 2 + 0) * 256);
            acc[t] = __builtin_amdgcn_mfma_f32_16x16x32_bf16(a0, b0, acc[t], 0, 0, 0);
            bfrag8 b1 = *(const bfrag8*)(bbase + (t * 2 + 1) * 256);
            acc[t] = __builtin_amdgcn_mfma_f32_16x16x32_bf16(a1, b1, acc[t], 0, 0, 0);
        }
    }

    // C/D layout (m89/m91-verified): m-row = 4q + r, n-col = 16t + c
    float* P = partials + (size_t)split * N_ROWS * 128 + (size_t)(16 * mwave) * 128;
#pragma unroll
    for (int t = 0; t < 8; t++)
#pragma unroll
        for (int r = 0; r < 4; r++)
            P[(4 * q + r) * 128 + 16 * t + c] = acc[t][r];
}

// ---------------------------------------------------------------------------
// Fallback GEMM (round 3, verified): direct from fp32 L, in case ws is small.
// ---------------------------------------------------------------------------
__global__ void __launch_bounds__(256, 3)
gemm_direct(const float* __restrict__ L, const uint32_t* __restrict__ Bimg,
            float* __restrict__ partials, int kpb) {
    const int tid  = threadIdx.x;
    const int lane = tid & 63;
    const int gw   = blockIdx.x * 4 + (tid >> 6);
    const int split = gw >> 9;
    const int mwave = gw & 511;
    const int c = lane & 15;
    const int q = lane >> 4;
    const float* lrow = L + (size_t)(16 * mwave + c) * D_DIM;

    facc4 acc[8];
#pragma unroll
    for (int t = 0; t < 8; t++) acc[t] = (facc4){0.f, 0.f, 0.f, 0.f};

    const int k0 = split * kpb;
#pragma unroll 2
    for (int k = k0; k < k0 + kpb; k++) {
        const int kc = k * 64;
        bfrag8 a[2];
#pragma unroll
        for (int ks = 0; ks < 2; ks++) {
            const float* p = lrow + kc + ks * 32 + q * 8;
            float4 f0 = *(const float4*)(p);
            float4 f1 = *(const float4*)(p + 4);
            uint4 u;
            u.x = pack_bf16x2(f0.x, f0.y);
            u.y = pack_bf16x2(f0.z, f0.w);
            u.z = pack_bf16x2(f1.x, f1.y);
            u.w = pack_bf16x2(f1.z, f1.w);
            a[ks] = *(bfrag8*)&u;
        }
        const uint32_t* bbase = Bimg + ((size_t)k * 16) * 256 + lane * 4;
#pragma unroll
        for (int t = 0; t < 8; t++) {
#pragma unroll
            for (int ks = 0; ks < 2; ks++) {
                bfrag8 b = *(const bfrag8*)(bbase + (t * 2 + ks) * 256);
                acc[t] = __builtin_amdgcn_mfma_f32_16x16x32_bf16(a[ks], b, acc[t], 0, 0, 0);
            }
        }
    }
    float* P = partials + (size_t)split * N_ROWS * 128 + (size_t)(16 * mwave) * 128;
#pragma unroll
    for (int t = 0; t < 8; t++)
#pragma unroll
        for (int r = 0; r < 4; r++)
            P[(4 * q + r) * 128 + 16 * t + c] = acc[t][r];
}

// ---------------------------------------------------------------------------
// Kernel 3: reduce S partial planes, sign -> 128-bit key -> 64-bit fold.
// ---------------------------------------------------------------------------
__global__ void __launch_bounds__(256)
reduce_pack(const float* __restrict__ partials, u64* __restrict__ folded, int S) {
    const int row  = blockIdx.x * 4 + (threadIdx.x >> 6);
    const int lane = threadIdx.x & 63;
    float s0 = 0.f, s1 = 0.f;
    for (int s = 0; s < S; s++) {
        const float* P = partials + ((size_t)s * N_ROWS * 128) + (size_t)row * 128;
        s0 += P[lane];
        s1 += P[lane + 64];
    }
    u64 b0 = __ballot(s0 > 0.0f);
    u64 b1 = __ballot(s1 > 0.0f);
    if (lane == 0) folded[row] = b0 ^ b1;
}

// ---------------------------------------------------------------------------
// Kernel 4: ordered duplicate count, LDS-staged keys (verified since round 2).
// ---------------------------------------------------------------------------
__global__ void __launch_bounds__(256)
count_rows(const u64* __restrict__ folded, float* __restrict__ out) {
    __shared__ u64 K[N_ROWS];
    const int tid = threadIdx.x;
    for (int i = tid; i < N_ROWS / 2; i += 256)
        ((uint4*)K)[i] = ((const uint4*)folded)[i];
    __syncthreads();

    const int g    = blockIdx.x * 4 + (tid >> 6);
    const int lane = tid & 63;
    int rows[4];
    u64 my[4];
    int cnt[4] = {0, 0, 0, 0};
#pragma unroll
    for (int r = 0; r < 4; r++) {
        rows[r] = g + 2048 * r;
        my[r] = K[rows[r]];
    }
    const int maxrow = rows[3];
    for (int j = lane; j <= maxrow; j += 64) {
        u64 k = K[j];
#pragma unroll
        for (int r = 0; r < 4; r++)
            cnt[r] += (int)((j <= rows[r]) & (k == my[r]));
    }
#pragma unroll
    for (int r = 0; r < 4; r++) {
        int v = cnt[r];
#pragma unroll
        for (int o = 32; o; o >>= 1) v += __shfl_xor(v, o, 64);
        if (lane == 0) out[rows[r]] = rsqrtf((float)v);
    }
}

extern "C" void kernel_launch(void* const* d_in, const int* in_sizes, int n_in,
                              void* d_out, int out_size, void* d_ws, size_t ws_size,
                              hipStream_t stream) {
    const float* latent = (const float*)d_in[0];   // [128,64,4096] fp32
    const float* A      = (const float*)d_in[1];   // [128,4096] fp32
    float* out          = (float*)d_out;           // [8192] fp32

    // ws: Bimg 1 MB | folded 64 KB | Lb 64 MB | partials 32 MB (S=8)
    const size_t OFF_FOLDED = (size_t)1 << 20;
    const size_t OFF_LB     = OFF_FOLDED + ((size_t)1 << 16);
    const size_t OFF_PART   = OFF_LB + ((size_t)64 << 20);
    const size_t NEED       = OFF_PART + ((size_t)32 << 20);

    uint32_t* Bimg = (uint32_t*)d_ws;
    u64* folded    = (u64*)((char*)d_ws + OFF_FOLDED);

    prep_A<<<256, 256, 0, stream>>>(A, Bimg);

    if (ws_size >= NEED) {
        uint32_t* Lb    = (uint32_t*)((char*)d_ws + OFF_LB);
        float* partials = (float*)((char*)d_ws + OFF_PART);
        copy_bf16<<<2048, 256, 0, stream>>>(latent, Lb);
        gemm_direct_b<<<128 * 8, 256, 0, stream>>>(Lb, Bimg, partials, 64 / 8);
        reduce_pack<<<2048, 256, 0, stream>>>(partials, folded, 8);
    } else {
        float* partials = (float*)((char*)d_ws + OFF_LB);
        const size_t per_split = (size_t)N_ROWS * 128 * sizeof(float);
        int S = 1;
        if (ws_size >= OFF_LB + 8 * per_split)      S = 8;
        else if (ws_size >= OFF_LB + 4 * per_split) S = 4;
        else if (ws_size >= OFF_LB + 2 * per_split) S = 2;
        gemm_direct<<<128 * S, 256, 0, stream>>>(latent, Bimg, partials, 64 / S);
        reduce_pack<<<2048, 256, 0, stream>>>(partials, folded, S);
    }
    count_rows<<<512, 256, 0, stream>>>(folded, out);
}